// Round 13
// baseline (770.121 us; speedup 1.0000x reference)
//
#include <hip/hip_runtime.h>

// Bidirectional masked LSTM, only last timestep consumed.
//   B=256, T=2048, VOCAB=6, EMB=64, HID=64.  One block per batch element/CU.
// Algebraic reductions (validated rounds 0-12, absmax 0.0):
//   - bwd direction at t=T-1 == ONE lstm step from zero state (U_b unused).
//   - x@W+b has only 6 values per direction -> zx tables.
//   - tok==0 steps are no-ops -> token stream compacted once.
// Ledger: R6/R12 = 703us @ VGPR=52 (identical codegen -> compiler dissolves
//   source-level scheduling); R9 AGPR volatile = 967; R10 AGPR sched = 862.
//   FETCH_SIZE 1855MB constant across all incl. memory-free loop = artifact.
// Round-13 ROOT CAUSE hypothesis: the register allocator targets its DEFAULT
//   occupancy (8 waves/EU = 64-VGPR budget); launch_bounds(256,1) only sets
//   the waves-per-eu MINIMUM. At a 64-reg budget 64 live U values can never
//   be kept -> spill to scratch -> per-step reload stalls. Real occupancy is
//   1 wave/EU anyway (4 waves, 1 block/CU).
//   FIX: __attribute__((amdgpu_waves_per_eu(1,1))) forces the RA to plan for
//   a 512-VGPR budget. Clean R3-style loop, no volatile/pins/hand-pipelining.
// Predicted: VGPR 52 -> ~120-180, dur 703 -> ~380-480us, VALUBusy -> 60-72%.

#define TT 2048
#define L2E 1.4426950408889634f

__device__ __forceinline__ float fexp2(float x) { return __builtin_amdgcn_exp2f(x); }
__device__ __forceinline__ float frcp(float x)  { return __builtin_amdgcn_rcpf(x); }
__device__ __forceinline__ float fsigm(float x) { return frcp(1.f + fexp2(-L2E * x)); }
__device__ __forceinline__ float ftanh(float x) { return fmaf(2.f, frcp(1.f + fexp2(-2.f * L2E * x)), -1.f); }
__device__ __forceinline__ float readlane_f(float v, int l) {
  return __builtin_bit_cast(float, __builtin_amdgcn_readlane(__builtin_bit_cast(int, v), l));
}

__global__ void
__attribute__((amdgpu_flat_work_group_size(256, 256)))
__attribute__((amdgpu_waves_per_eu(1, 1)))
lstm_fused(
    const int* __restrict__ tokens,
    const float* __restrict__ emb,
    const float* __restrict__ W_f, const float* __restrict__ U_f, const float* __restrict__ b_f,
    const float* __restrict__ W_b, const float* __restrict__ b_b,
    const float* __restrict__ W_d, const float* __restrict__ b_d,
    float* __restrict__ out)
{
  const int b    = blockIdx.x;
  const int tid  = threadIdx.x;
  const int lane = tid & 63;      // unit u = lane
  const int g    = tid >> 6;      // wave == gate: 0:i 1:f 2:g(tanh) 3:o

  __shared__ int   tok_s [TT + 8];
  __shared__ int   ctok_s[TT + 8];      // compacted active tokens
  __shared__ float emb_s[6 * 64];
  __shared__ float zx_s [6 * 272];      // fwd table, [v][g*68 + u] (padded)
  __shared__ float zxb_s[6 * 256];      // bwd table (epilogue only)
  __shared__ float act_s[2][4 * 68];    // [buf][g*68 + u]
  __shared__ int   wsum[4];

  // ---- stage tokens (int4) + emb ----
  {
    const int4* tsrc = (const int4*)(tokens + b * TT);
    int4* tdst = (int4*)tok_s;
    for (int i = tid; i < TT / 4; i += 256) tdst[i] = tsrc[i];
    if (tid < 8) { tok_s[TT + tid] = 0; ctok_s[TT + tid] = 0; }
    for (int i = tid; i < 384; i += 256) emb_s[i] = emb[i];
  }
  __syncthreads();

  // ---- compact active tokens: stable parallel scan (8 tokens/thread) ----
  int mytok[8];
  int cnt = 0;
#pragma unroll
  for (int j = 0; j < 8; ++j) {
    mytok[j] = tok_s[tid * 8 + j];
    cnt += (mytok[j] != 0);
  }
  int inc = cnt;                        // wave-inclusive scan
#pragma unroll
  for (int off = 1; off < 64; off <<= 1) {
    int v = __shfl_up(inc, off, 64);
    if (lane >= off) inc += v;
  }
  if (lane == 63) wsum[g] = inc;
  __syncthreads();
  int base = 0;
#pragma unroll
  for (int w = 0; w < 4; ++w) base += (w < g) ? wsum[w] : 0;
  int pos = base + inc - cnt;           // exclusive global offset
#pragma unroll
  for (int j = 0; j < 8; ++j)
    if (mytok[j] != 0) ctok_s[pos++] = mytok[j];
  const int nact = __builtin_amdgcn_readfirstlane(wsum[0] + wsum[1] + wsum[2] + wsum[3]);

  // ---- zx tables (thread owns column (g,lane), both dirs) ----
  {
    float af[6], ab[6];
#pragma unroll
    for (int v = 0; v < 6; ++v) { af[v] = b_f[tid]; ab[v] = b_b[tid]; }
    for (int e = 0; e < 64; ++e) {
      const float wf = W_f[e * 256 + tid];
      const float wb = W_b[e * 256 + tid];
#pragma unroll
      for (int v = 0; v < 6; ++v) {
        af[v] = fmaf(emb_s[v * 64 + e], wf, af[v]);
        ab[v] = fmaf(emb_s[v * 64 + e], wb, ab[v]);
      }
    }
#pragma unroll
    for (int v = 0; v < 6; ++v) {
      zx_s [v * 272 + g * 68 + lane] = af[v];
      zxb_s[v * 256 + tid] = ab[v];
    }
  }

  // ---- U column for (gate g, unit lane): plain register array.
  //      With waves_per_eu(1,1) the RA has a 512-VGPR budget -> stays
  //      register-resident with no spills (this is the round's test). ----
  float Ucol[64];
#pragma unroll
  for (int k = 0; k < 64; ++k) Ucol[k] = U_f[k * 256 + tid];

  __syncthreads();

  // wave-uniform activation constants: y = ya*rcp(1+exp2(z*m1)) + yb
  const float m1 = (g == 2) ? (-2.f * L2E) : (-L2E);
  const float ya = (g == 2) ? 2.f : 1.f;
  const float yb = (g == 2) ? -1.f : 0.f;
  const int   goff = g * 68 + lane;

  // h,c replicated per-lane in EVERY wave: lane l holds h[l], c[l]
  float h_reg = 0.f, c_reg = 0.f;
  int   buf = 0;
  int   tokc = ctok_s[0];

  for (int s = 0; s < nact; ++s) {
    const int tokn = ctok_s[s + 1];              // prefetch (pad-safe)
    const float zxv = zx_s[tokc * 272 + goff];   // issues under FMA block
    float a0 = 0.f, a1 = 0.f, a2 = 0.f, a3 = 0.f;
#pragma unroll
    for (int k = 0; k < 64; k += 4) {
      a0 = fmaf(readlane_f(h_reg, k + 0), Ucol[k + 0], a0);
      a1 = fmaf(readlane_f(h_reg, k + 1), Ucol[k + 1], a1);
      a2 = fmaf(readlane_f(h_reg, k + 2), Ucol[k + 2], a2);
      a3 = fmaf(readlane_f(h_reg, k + 3), Ucol[k + 3], a3);
    }
    const float z = zxv + ((a0 + a1) + (a2 + a3));
    const float y = fmaf(ya, frcp(1.f + fexp2(z * m1)), yb);
    act_s[buf][goff] = y;
    __syncthreads();
    const float ai  = act_s[buf][lane];
    const float af2 = act_s[buf][68 + lane];
    const float ag  = act_s[buf][136 + lane];
    const float ao  = act_s[buf][204 + lane];
    c_reg = fmaf(af2, c_reg, ai * ag);           // replicated update, all waves
    h_reg = ao * ftanh(c_reg);
    buf ^= 1;                                    // WAR-safe: 2 barriers apart
    tokc = tokn;
  }

  // ---- epilogue: bwd single step from zero state + dense + reduce ----
  if (tid < 64) {                                // wave 0 holds h[lane] = h_reg
    const float hf   = h_reg;
    const int   tokL = tok_s[TT - 1];
    float hbv = 0.f;
    if (tokL != 0) {
      const float zi = zxb_s[tokL * 256 + tid];
      const float zg = zxb_s[tokL * 256 + 128 + tid];
      const float zo = zxb_s[tokL * 256 + 192 + tid];
      const float cn = fsigm(zi) * ftanh(zg);    // c0=0 -> forget term vanishes
      hbv = fsigm(zo) * ftanh(cn);
    }
    float pr = fmaf(hf, W_d[tid], hbv * W_d[64 + tid]);
#pragma unroll
    for (int off = 32; off > 0; off >>= 1) pr += __shfl_xor(pr, off, 64);
    if (tid == 0) out[b] = pr + b_d[0];
  }
}

extern "C" void kernel_launch(void* const* d_in, const int* in_sizes, int n_in,
                              void* d_out, int out_size, void* d_ws, size_t ws_size,
                              hipStream_t stream) {
  const int*   tokens = (const int*)d_in[0];
  const float* emb    = (const float*)d_in[1];
  const float* W_f    = (const float*)d_in[2];
  const float* U_f    = (const float*)d_in[3];
  const float* b_f    = (const float*)d_in[4];
  const float* W_b    = (const float*)d_in[5];
  const float* U_b    = (const float*)d_in[6];
  (void)U_b;  // bwd is a single step from zero state: h@U_b == 0
  const float* b_b    = (const float*)d_in[7];
  const float* W_d    = (const float*)d_in[8];
  const float* b_d    = (const float*)d_in[9];
  float* out = (float*)d_out;
  (void)d_ws; (void)ws_size;

  lstm_fused<<<256, 256, 0, stream>>>(tokens, emb, W_f, U_f, b_f, W_b, b_b,
                                      W_d, b_d, out);
}